// Round 1
// baseline (620.595 us; speedup 1.0000x reference)
//
#include <hip/hip_runtime.h>

// Problem constants (from reference): B=262144, C=6, P=64
// out[b, c*P + p] = heaviside(mem_new - thr[c])
// mem_new = beta[c]*mem + (x[b,c]*W[c,p] + b[c,p]) - heaviside(mem - thr[c])*thr[c]
//
// Numerics: numpy reference uses separately-rounded mul/add. We use __fmul_rn /
// __fadd_rn / __fsub_rn to forbid FMA contraction so the heaviside boundary
// comparisons are bit-identical to the reference.

#define BB 262144
#define CC 6
#define PP 64

__device__ __constant__ float BETA_C[6] = {0.9f, 0.85f, 0.9f, 0.85f, 0.9f, 0.85f};
__device__ __constant__ float THR_C[6]  = {1.0f, 1.0f, 1.0f, 1.0f, 1.0f, 1.0f};

__global__ __launch_bounds__(256) void snn_encoder_kernel(
    const float* __restrict__ x,    // (B, C)
    const float* __restrict__ W,    // (C, P)
    const float* __restrict__ bias, // (C, P)
    const float* __restrict__ mem,  // (B, C, P)
    float* __restrict__ out)        // (B, C*P)
{
    const int tid = blockIdx.x * blockDim.x + threadIdx.x;
    const int total4 = (BB * CC * PP) / 4;   // 25,165,824
    if (tid >= total4) return;

    const int j = tid << 2;          // flat element index, < 2^27 -- fits int
    const int r = j >> 6;            // row index = b*C + c  (== flat x index)
    const int p = j & 63;            // position within P, 4-aligned
    const int c = r % 6;

    const float xv   = x[r];
    const float beta = BETA_C[c];
    const float thr  = THR_C[c];

    const float4 wv = *reinterpret_cast<const float4*>(W    + c * PP + p);
    const float4 bv = *reinterpret_cast<const float4*>(bias + c * PP + p);
    const float4 mv = *reinterpret_cast<const float4*>(mem  + j);

    float4 o;
    {
        // component x
        float cur   = __fadd_rn(__fmul_rn(xv, wv.x), bv.x);
        float rterm = (mv.x > thr) ? thr : 0.0f;               // reset * thr
        float mn    = __fsub_rn(__fadd_rn(__fmul_rn(beta, mv.x), cur), rterm);
        o.x = (mn > thr) ? 1.0f : 0.0f;
    }
    {
        float cur   = __fadd_rn(__fmul_rn(xv, wv.y), bv.y);
        float rterm = (mv.y > thr) ? thr : 0.0f;
        float mn    = __fsub_rn(__fadd_rn(__fmul_rn(beta, mv.y), cur), rterm);
        o.y = (mn > thr) ? 1.0f : 0.0f;
    }
    {
        float cur   = __fadd_rn(__fmul_rn(xv, wv.z), bv.z);
        float rterm = (mv.z > thr) ? thr : 0.0f;
        float mn    = __fsub_rn(__fadd_rn(__fmul_rn(beta, mv.z), cur), rterm);
        o.z = (mn > thr) ? 1.0f : 0.0f;
    }
    {
        float cur   = __fadd_rn(__fmul_rn(xv, wv.w), bv.w);
        float rterm = (mv.w > thr) ? thr : 0.0f;
        float mn    = __fsub_rn(__fadd_rn(__fmul_rn(beta, mv.w), cur), rterm);
        o.w = (mn > thr) ? 1.0f : 0.0f;
    }

    *reinterpret_cast<float4*>(out + j) = o;
}

extern "C" void kernel_launch(void* const* d_in, const int* in_sizes, int n_in,
                              void* d_out, int out_size, void* d_ws, size_t ws_size,
                              hipStream_t stream) {
    const float* x    = (const float*)d_in[0];  // (B, C)
    const float* W    = (const float*)d_in[1];  // (C, P)
    const float* bias = (const float*)d_in[2];  // (C, P)
    const float* mem  = (const float*)d_in[3];  // (B, C, P)
    float* out = (float*)d_out;                 // (B, C*P)

    const int total4 = (BB * CC * PP) / 4;      // 25,165,824
    const int block  = 256;
    const int grid   = (total4 + block - 1) / block;  // 98,304

    snn_encoder_kernel<<<grid, block, 0, stream>>>(x, W, bias, mem, out);
}